// Round 1
// baseline (4265.290 us; speedup 1.0000x reference)
//
#include <hip/hip_runtime.h>

// GridRNN: B=4, S=T=128, H=256, D=3.
// X-recurrence runs along diagonals (chain r: cells (i, (r+i) mod 128)),
// Y-recurrence along rows. 1024 independent chains per depth.
// One kernel per depth; intermediates stored in-place in d_out's two H-slots.

#define SS 128
#define TT 128
#define HH 256
#define NP 128  // HH/2 f16 pairs

typedef _Float16 half2v __attribute__((ext_vector_type(2)));

__device__ __forceinline__ float fdot2f(half2v a, half2v b, float c) {
#if __has_builtin(__builtin_amdgcn_fdot2)
    return __builtin_amdgcn_fdot2(a, b, c, false);
#else
    return c + (float)a[0] * (float)b[0] + (float)a[1] * (float)b[1];
#endif
}

__device__ __forceinline__ float fast_tanh(float x) {
    // tanh(x) = 1 - 2/(exp(2x)+1); saturates correctly for |x| large.
    float e = __expf(2.0f * x);
    return 1.0f - 2.0f / (e + 1.0f);
}

extern "C" __global__ void __launch_bounds__(256, 1)
grid_rnn_depth(const float* __restrict__ src, const float* __restrict__ trg,
               const float* __restrict__ Wx_ih, const float* __restrict__ Wx_hh,
               const float* __restrict__ bx_ih, const float* __restrict__ bx_hh,
               const float* __restrict__ Wy_ih, const float* __restrict__ Wy_hh,
               const float* __restrict__ by_ih, const float* __restrict__ by_hh,
               float* out, int d)
{
    __shared__ __align__(8) _Float16 lds_x[HH];
    __shared__ __align__(8) _Float16 lds_h[HH];

    const int t = threadIdx.x;              // output element n = t
    const int bid = blockIdx.x;             // 0..255
    const bool isY = bid >= 128;
    const int g = isY ? (bid - 128) : bid;  // 0..127 within direction
    const int b = g >> 5;                   // batch 0..3
    const int c0 = (g & 31) << 2;           // first of 4 chains (r for X, i for Y)

    const float* Wih = (isY ? Wy_ih : Wx_ih) + d * HH * HH;
    const float* Whh = (isY ? Wy_hh : Wx_hh) + d * HH * HH;
    const float bias = (isY ? by_ih : bx_ih)[d * HH + t]
                     + (isY ? by_hh : bx_hh)[d * HH + t];

    // Thread-private weight rows (row t of each matrix), f16-packed: 256 VGPRs.
    half2v wih[NP], whh[NP];
    {
        const float2* ri = (const float2*)(Wih + t * HH);
        const float2* rh = (const float2*)(Whh + t * HH);
#pragma unroll
        for (int k = 0; k < NP; ++k) {
            float2 u = ri[k];
            float2 v = rh[k];
            half2v wa = { (_Float16)u.x, (_Float16)u.y };
            half2v wb = { (_Float16)v.x, (_Float16)v.y };
            wih[k] = wa;
            whh[k] = wb;
        }
    }

    const half2v* vx = (const half2v*)lds_x;
    const half2v* vh = (const half2v*)lds_h;

    for (int cc = 0; cc < 4; ++cc) {
        const int chain = c0 + cc;
        float hprev = 0.0f;                  // initial state = 0 (incl. rolled j wrap)
        for (int s = 0; s < 128; ++s) {
            const int i = isY ? chain : s;
            const int j = isY ? s : ((chain + s) & 127);
            const size_t cell = (size_t)((b * SS + i) * TT + j) * (2 * HH);
            const int slot = isY ? HH : 0;

            // Input term source: depth 0 reads broadcast src/trg; d>0 reads the
            // previous depth's h at this very cell (only this chain touches it,
            // and we read before we overwrite -> in-place is race-free).
            const float* xrow = (d == 0)
                ? (isY ? (trg + (b * TT + j) * HH) : (src + (b * SS + i) * HH))
                : (out + cell + slot);
            const float xv = xrow[t];

            __syncthreads();                 // prior step's LDS reads complete
            lds_x[t] = (_Float16)xv;
            lds_h[t] = (_Float16)hprev;
            __syncthreads();

            float a0 = bias, a1 = 0.f, a2 = 0.f, a3 = 0.f;
            float a4 = 0.f,  a5 = 0.f, a6 = 0.f, a7 = 0.f;
#pragma unroll
            for (int k = 0; k < NP; k += 4) {
                a0 = fdot2f(wih[k + 0], vx[k + 0], a0);
                a1 = fdot2f(wih[k + 1], vx[k + 1], a1);
                a2 = fdot2f(wih[k + 2], vx[k + 2], a2);
                a3 = fdot2f(wih[k + 3], vx[k + 3], a3);
                a4 = fdot2f(whh[k + 0], vh[k + 0], a4);
                a5 = fdot2f(whh[k + 1], vh[k + 1], a5);
                a6 = fdot2f(whh[k + 2], vh[k + 2], a6);
                a7 = fdot2f(whh[k + 3], vh[k + 3], a7);
            }
            const float h = fast_tanh(((a0 + a1) + (a2 + a3)) + ((a4 + a5) + (a6 + a7)));
            out[cell + slot + t] = h;
            hprev = h;
        }
    }
}

extern "C" void kernel_launch(void* const* d_in, const int* in_sizes, int n_in,
                              void* d_out, int out_size, void* d_ws, size_t ws_size,
                              hipStream_t stream) {
    const float* src   = (const float*)d_in[0];
    const float* trg   = (const float*)d_in[1];
    const float* Wx_ih = (const float*)d_in[2];
    const float* Wx_hh = (const float*)d_in[3];
    const float* bx_ih = (const float*)d_in[4];
    const float* bx_hh = (const float*)d_in[5];
    const float* Wy_ih = (const float*)d_in[6];
    const float* Wy_hh = (const float*)d_in[7];
    const float* by_ih = (const float*)d_in[8];
    const float* by_hh = (const float*)d_in[9];
    float* out = (float*)d_out;

    for (int d = 0; d < 3; ++d) {
        hipLaunchKernelGGL(grid_rnn_depth, dim3(256), dim3(256), 0, stream,
                           src, trg, Wx_ih, Wx_hh, bx_ih, bx_hh,
                           Wy_ih, Wy_hh, by_ih, by_hh, out, d);
    }
}

// Round 2
// 831.192 us; speedup vs baseline: 5.1315x; 5.1315x over previous
//
#include <hip/hip_runtime.h>

// GridRNN B=4, S=T=128, H=256, D=3 — MFMA version.
// 16 chains per workgroup -> per step: [16x256] @ [256x256]^T x2 via
// mfma_f32_16x16x32_f16. 64 wgs (32 X-diagonal-chain groups, 32 Y-row groups).
// LDS holds A-operands in MFMA fragment cell order: cell c=f*64+q*16+m holds
// A[m][k=f*32+q*8 .. +7] as 8 f16 (16B) -> ds_read_b128 at (f*64+lane)*16.

#define SS 128
#define TT 128
#define HH 256
#define GRID_ELEMS ((size_t)4 * 128 * 128 * 256)  // one direction's h-grid

typedef _Float16 half8 __attribute__((ext_vector_type(8)));
typedef float float4v __attribute__((ext_vector_type(4)));

__device__ __forceinline__ float fast_tanh(float x) {
    float e = __expf(2.0f * x);
    return 1.0f - 2.0f / (e + 1.0f);
}

__device__ __forceinline__ unsigned short f2hbits(float x) {
    _Float16 h = (_Float16)x;
    return __builtin_bit_cast(unsigned short, h);
}

extern "C" __global__ void __launch_bounds__(512, 2)
grid_rnn_mfma(const float* __restrict__ src, const float* __restrict__ trg,
              const float* __restrict__ Wx_ih, const float* __restrict__ Wx_hh,
              const float* __restrict__ bx_ih, const float* __restrict__ bx_hh,
              const float* __restrict__ Wy_ih, const float* __restrict__ Wy_hh,
              const float* __restrict__ by_ih, const float* __restrict__ by_hh,
              float* __restrict__ out, unsigned short* __restrict__ ws,
              int d, int use_ws)
{
    __shared__ half8 aX[2][512];   // x-input A-frags, double buffered (8 KB x2)
    __shared__ half8 aH[512];      // h-state A-frags (8 KB)

    const int tid  = threadIdx.x;
    const int lane = tid & 63;
    const int wv   = tid >> 6;     // wave 0..7 -> N-slice n0 = 32*wv
    const int quad = lane >> 4;
    const int l15  = lane & 15;

    const int bid  = blockIdx.x;   // 0..63
    const int isY  = bid >= 32;
    const int g    = isY ? bid - 32 : bid;
    const int b    = g >> 3;       // batch
    const int c0   = (g & 7) << 4; // first chain of the 16-chain group
    const int slot = isY;

    const float* Wih = (isY ? Wy_ih : Wx_ih) + (size_t)d * HH * HH;
    const float* Whh = (isY ? Wy_hh : Wx_hh) + (size_t)d * HH * HH;
    const float* bih = (isY ? by_ih : bx_ih) + d * HH;
    const float* bhh = (isY ? by_hh : bx_hh) + d * HH;
    unsigned short* wsg = ws + (size_t)isY * GRID_ELEMS;

    const int n0  = wv << 5;
    const int n_0 = n0 + l15;        // tile-0 column
    const int n_1 = n_0 + 16;        // tile-1 column

    // ---- B fragments (weights), resident in VGPRs: 32 x half8 = 128 VGPRs.
    // B[k=f*32+quad*8+j][n] = W[n][k] -> lane reads 8 consecutive floats of row n.
    half8 Bih0[8], Bih1[8], Bhh0[8], Bhh1[8];
    {
        const float* r0i = Wih + (size_t)n_0 * HH;
        const float* r1i = Wih + (size_t)n_1 * HH;
        const float* r0h = Whh + (size_t)n_0 * HH;
        const float* r1h = Whh + (size_t)n_1 * HH;
        auto ldfrag = [&](const float* rowp, int k) -> half8 {
            const float4v u0 = *(const float4v*)(rowp + k);
            const float4v u1 = *(const float4v*)(rowp + k + 4);
            half8 v;
#pragma unroll
            for (int t = 0; t < 4; ++t) { v[t] = (_Float16)u0[t]; v[4 + t] = (_Float16)u1[t]; }
            return v;
        };
#pragma unroll
        for (int f = 0; f < 8; ++f) {
            const int k = (f << 5) + (quad << 3);
            Bih0[f] = ldfrag(r0i, k);
            Bih1[f] = ldfrag(r1i, k);
            Bhh0[f] = ldfrag(r0h, k);
            Bhh1[f] = ldfrag(r1h, k);
        }
    }
    const float bias0 = bih[n_0] + bhh[n_0];
    const float bias1 = bih[n_1] + bhh[n_1];

    // ---- staging: thread tid owns A-frag cell c=tid: row m=c&15, k0=(c>>4)*8.
    const int cm  = tid & 15;
    const int ck0 = (tid >> 4) << 3;
    const int chc = c0 + cm;

    auto stage = [&](int sn) -> half8 {
        const int i = isY ? chc : sn;
        const int j = isY ? sn : ((chc + sn) & 127);
        const size_t cell = (size_t)(b * SS + i) * TT + j;
        half8 v;
        if (d == 0) {
            const float* row = isY ? (trg + (size_t)(b * TT + j) * HH)
                                   : (src + (size_t)(b * SS + i) * HH);
            const float4v u0 = *(const float4v*)(row + ck0);
            const float4v u1 = *(const float4v*)(row + ck0 + 4);
#pragma unroll
            for (int t = 0; t < 4; ++t) { v[t] = (_Float16)u0[t]; v[4 + t] = (_Float16)u1[t]; }
        } else if (use_ws) {
            v = *(const half8*)(wsg + cell * HH + ck0);
        } else {
            const float* row = out + cell * 2 * HH + (size_t)slot * HH + ck0;
            const float4v u0 = *(const float4v*)(row);
            const float4v u1 = *(const float4v*)(row + 4);
#pragma unroll
            for (int t = 0; t < 4; ++t) { v[t] = (_Float16)u0[t]; v[4 + t] = (_Float16)u1[t]; }
        }
        return v;
    };

    // ---- init: stage step 0, zero h-state frags.
    aX[0][tid] = stage(0);
    {
        half8 z;
#pragma unroll
        for (int t = 0; t < 8; ++t) z[t] = (_Float16)0.f;
        aH[tid] = z;
    }
    __syncthreads();

    const int cellbase0 = ((n_0 >> 5) << 6) + (((n_0 >> 3) & 3) << 4);
    const int cellbase1 = ((n_1 >> 5) << 6) + (((n_1 >> 3) & 3) << 4);

    int buf = 0;
    for (int s = 0; s < 128; ++s) {
        // phase 1: A-frags from LDS (lane-contiguous b128, conflict-free)
        half8 axr[8], ahr[8];
#pragma unroll
        for (int f = 0; f < 8; ++f) {
            axr[f] = aX[buf][(f << 6) + lane];
            ahr[f] = aH[(f << 6) + lane];
        }
        __syncthreads();

        // phase 2: prefetch next step's x-input (hidden behind MFMAs)
        half8 px;
        const int pf = (s + 1 < 128);
        if (pf) px = stage(s + 1);

        // phase 3: D = Xin@Wih^T + Hprev@Whh^T + bias  (32 MFMAs, 2 acc chains)
        float4v acc0 = {bias0, bias0, bias0, bias0};
        float4v acc1 = {bias1, bias1, bias1, bias1};
#pragma unroll
        for (int f = 0; f < 8; ++f) {
            acc0 = __builtin_amdgcn_mfma_f32_16x16x32_f16(axr[f], Bih0[f], acc0, 0, 0, 0);
            acc1 = __builtin_amdgcn_mfma_f32_16x16x32_f16(axr[f], Bih1[f], acc1, 0, 0, 0);
            acc0 = __builtin_amdgcn_mfma_f32_16x16x32_f16(ahr[f], Bhh0[f], acc0, 0, 0, 0);
            acc1 = __builtin_amdgcn_mfma_f32_16x16x32_f16(ahr[f], Bhh1[f], acc1, 0, 0, 0);
        }

        // phase 4/5: tanh, store h to global, scatter h into aH in A-frag order
        unsigned short* aHu = (unsigned short*)aH;
#pragma unroll
        for (int r = 0; r < 4; ++r) {
            const float h0 = fast_tanh(acc0[r]);
            const float h1 = fast_tanh(acc1[r]);
            const int m = (quad << 2) + r;       // C/D row = chain-in-group
            const int chain = c0 + m;
            const int i = isY ? chain : s;
            const int j = isY ? s : ((chain + s) & 127);
            const size_t cell = (size_t)(b * SS + i) * TT + j;
            if (!use_ws || d == 2) {
                float* orow = out + cell * 2 * HH + (size_t)slot * HH;
                orow[n_0] = h0;
                orow[n_1] = h1;
            }
            if (use_ws && d < 2) {
                unsigned short* wrow = wsg + cell * HH;
                wrow[n_0] = f2hbits(h0);
                wrow[n_1] = f2hbits(h1);
            }
            aHu[((cellbase0 + m) << 3) + (n_0 & 7)] = f2hbits(h0);
            aHu[((cellbase1 + m) << 3) + (n_1 & 7)] = f2hbits(h1);
        }
        if (pf) aX[buf ^ 1][tid] = px;
        __syncthreads();
        buf ^= 1;
    }
    (void)wv;
}

extern "C" void kernel_launch(void* const* d_in, const int* in_sizes, int n_in,
                              void* d_out, int out_size, void* d_ws, size_t ws_size,
                              hipStream_t stream) {
    const float* src   = (const float*)d_in[0];
    const float* trg   = (const float*)d_in[1];
    const float* Wx_ih = (const float*)d_in[2];
    const float* Wx_hh = (const float*)d_in[3];
    const float* bx_ih = (const float*)d_in[4];
    const float* bx_hh = (const float*)d_in[5];
    const float* Wy_ih = (const float*)d_in[6];
    const float* Wy_hh = (const float*)d_in[7];
    const float* by_ih = (const float*)d_in[8];
    const float* by_hh = (const float*)d_in[9];
    float* out = (float*)d_out;
    unsigned short* ws = (unsigned short*)d_ws;

    const size_t need = 2 * GRID_ELEMS * sizeof(unsigned short);  // 67.1 MB
    const int use_ws = (ws_size >= need) ? 1 : 0;

    for (int d = 0; d < 3; ++d) {
        hipLaunchKernelGGL(grid_rnn_mfma, dim3(64), dim3(512), 0, stream,
                           src, trg, Wx_ih, Wx_hh, bx_ih, bx_hh,
                           Wy_ih, Wy_hh, by_ih, by_hh, out, ws, d, use_ws);
    }
}